// Round 6
// baseline (5722.734 us; speedup 1.0000x reference)
//
#include <hip/hip_runtime.h>

#define HD 64
#define WD 64
#define HW 4096
#define BATCH 2

// ---------------- weight transpose: w[o][c][k] -> wt[(c*9+k)*O + o] (fp32) ---
__global__ void transpose_w_k(const float* __restrict__ w, float* __restrict__ wt,
                              int O, int Ci) {
    int idx = blockIdx.x * 256 + threadIdx.x;
    int total = O * Ci * 9;
    if (idx >= total) return;
    int k = idx % 9;
    int c = (idx / 9) % Ci;
    int o = idx / (9 * Ci);
    wt[(size_t)(c * 9 + k) * O + o] = w[idx];
}

// ---------------- feat = concat(inputs[2b+a0], inputs[2b+1]) (f32 -> f64) ----
__global__ void pack_feat_d(const float* __restrict__ in, double* __restrict__ dst,
                            int a0) {
    int idx = blockIdx.x * 256 + threadIdx.x;
    if (idx >= BATCH * 256 * HW) return;
    int i = idx % HW;
    int c = (idx / HW) & 255;
    int b = idx / (HW * 256);
    int sb = 2 * b + ((c < 128) ? a0 : 1);
    dst[idx] = (double)in[((size_t)(sb * 128 + (c & 127))) * HW + i];
}

// ---------------- row-block conv3x3: 1 wave = (b,h) row x NO outputs ---------
// Grid (O/NO, HD, B). Weights original layout [o][ci][9], block-uniform reads.
template <int NO, int CC>
__global__ __launch_bounds__(64) void conv3x3_rowblk_d(
    const double* __restrict__ src, int bstride,
    const float* __restrict__ w, double* __restrict__ dst,
    int Ci, int O, int relu) {
    int x  = threadIdx.x;          // 0..63
    int og = blockIdx.x;
    int h  = blockIdx.y;
    int b  = blockIdx.z;
    int o0 = og * NO;

    __shared__ double s_rows[CC][3][66];   // col = gx+1, gx in [-1,64]

    double acc[NO];
#pragma unroll
    for (int i = 0; i < NO; ++i) acc[i] = 0.0;

    const double* sb = src + (size_t)b * bstride;
    for (int c0 = 0; c0 < Ci; c0 += CC) {
        __syncthreads();
        for (int i = x; i < CC * 198; i += 64) {
            int col = i % 66;
            int r   = (i / 66) % 3;
            int c   = i / 198;
            int gx  = col - 1;
            int y   = h + r - 1;
            double v = 0.0;
            if ((unsigned)gx < (unsigned)WD && (unsigned)y < (unsigned)HD)
                v = sb[(size_t)(c0 + c) * HW + y * WD + gx];
            s_rows[c][r][col] = v;
        }
        __syncthreads();
        for (int c = 0; c < CC; ++c) {
            // block-uniform weight addresses -> scalar loads
            const float* wc = w + ((size_t)o0 * Ci + (c0 + c)) * 9;
            float wr[NO][9];
#pragma unroll
            for (int oi = 0; oi < NO; ++oi)
#pragma unroll
                for (int k = 0; k < 9; ++k)
                    wr[oi][k] = wc[(size_t)oi * Ci * 9 + k];
#pragma unroll
            for (int kh = 0; kh < 3; ++kh) {
                double v0 = s_rows[c][kh][x];
                double v1 = s_rows[c][kh][x + 1];
                double v2 = s_rows[c][kh][x + 2];
#pragma unroll
                for (int oi = 0; oi < NO; ++oi) {
                    acc[oi] = fma(v0, (double)wr[oi][kh * 3 + 0], acc[oi]);
                    acc[oi] = fma(v1, (double)wr[oi][kh * 3 + 1], acc[oi]);
                    acc[oi] = fma(v2, (double)wr[oi][kh * 3 + 2], acc[oi]);
                }
            }
        }
    }
#pragma unroll
    for (int oi = 0; oi < NO; ++oi) {
        int o = o0 + oi;
        if (o < O) {
            double v = acc[oi];
            if (relu) v = fmax(v, 0.0);
            dst[((size_t)(b * O + o) * HD + h) * WD + x] = v;
        }
    }
}

// ---------------- direct conv3x3 (only for tiny O=1 final S-conv) ------------
__global__ __launch_bounds__(256) void conv3x3_direct_d(
    const double* __restrict__ src, int bstride,
    const float* __restrict__ w, double* __restrict__ dst,
    int Ci, int O, int relu) {
    int idx = blockIdx.x * 256 + threadIdx.x;
    int total = BATCH * O * HW;
    if (idx >= total) return;
    int x = idx & (WD - 1);
    int h = (idx >> 6) & (HD - 1);
    int rest = idx >> 12;
    int o = rest % O;
    int b = rest / O;
    const double* s  = src + (size_t)b * bstride + h * WD + x;
    const float*  wo = w + (size_t)o * Ci * 9;
    bool ym = (h > 0), yp = (h < HD - 1);
    bool xm = (x > 0), xp = (x < WD - 1);
    double a0 = 0.0, a1 = 0.0, a2 = 0.0;
    for (int c = 0; c < Ci; ++c) {
        const double* sc = s + (size_t)c * HW;
        const float*  wc = wo + c * 9;
        if (ym) {
            double v0 = xm ? sc[-WD - 1] : 0.0;
            double v1 = sc[-WD];
            double v2 = xp ? sc[-WD + 1] : 0.0;
            a0 = fma(v0, (double)wc[0], a0);
            a0 = fma(v1, (double)wc[1], a0);
            a0 = fma(v2, (double)wc[2], a0);
        }
        {
            double v0 = xm ? sc[-1] : 0.0;
            double v1 = sc[0];
            double v2 = xp ? sc[1] : 0.0;
            a1 = fma(v0, (double)wc[3], a1);
            a1 = fma(v1, (double)wc[4], a1);
            a1 = fma(v2, (double)wc[5], a1);
        }
        if (yp) {
            double v0 = xm ? sc[WD - 1] : 0.0;
            double v1 = sc[WD];
            double v2 = xp ? sc[WD + 1] : 0.0;
            a2 = fma(v0, (double)wc[6], a2);
            a2 = fma(v1, (double)wc[7], a2);
            a2 = fma(v2, (double)wc[8], a2);
        }
    }
    double acc = (a0 + a1) + a2;
    if (relu) acc = fmax(acc, 0.0);
    dst[idx] = acc;
}

// ---------------- fused deformable conv + GEMM, fp64 -------------------------
// Block = O threads; thread t: og=t>>2 (4 o's), pg=t&3 (4 px). 16-px tile.
template <int O, int CC, typename ST>
__global__ __launch_bounds__(O) void deform_gemm_d(
    const ST* __restrict__ src, int src_bstride,
    const double* __restrict__ off,
    const float* __restrict__ wt,   // [(c*9+k)*O + o]
    double* __restrict__ dst, int Ci) {
    int px0 = blockIdx.x * 16;
    int h   = blockIdx.y;
    int b   = blockIdx.z;
    int t   = threadIdx.x;
    int og  = t >> 2;
    int pg  = t & 3;

    __shared__ double s_samp[CC][9][16];
    __shared__ int    s_addr[9][16][4];
    __shared__ double s_w4[9][16][4];

    // phase 1: 144 sampling positions (shared across all channels)
    for (int i = t; i < 144; i += O) {
        int k = i / 16, px = i % 16, wc = px0 + px;
        double dy = off[((size_t)(b * 18 + 2 * k)     * HD + h) * WD + wc];
        double dx = off[((size_t)(b * 18 + 2 * k + 1) * HD + h) * WD + wc];
        double py  = dy + (double)(k / 3 - 1 + h);
        double pxf = dx + (double)(k % 3 - 1 + wc);
        double y0f = floor(py), x0f = floor(pxf);
        double wy1 = py - y0f, wx1 = pxf - x0f;
        double wy0 = 1.0 - wy1, wx0 = 1.0 - wx1;
        double y0c = fmax(-2.0, fmin(66.0, y0f));
        double x0c = fmax(-2.0, fmin(66.0, x0f));
        int y0 = (int)y0c, x0 = (int)x0c;
        int y1 = y0 + 1,   x1 = x0 + 1;
        bool vy0 = (y0 >= 0 && y0 < HD), vy1 = (y1 >= 0 && y1 < HD);
        bool vx0 = (x0 >= 0 && x0 < WD), vx1 = (x1 >= 0 && x1 < WD);
        int yc0 = min(max(y0, 0), HD - 1), yc1 = min(max(y1, 0), HD - 1);
        int xc0 = min(max(x0, 0), WD - 1), xc1 = min(max(x1, 0), WD - 1);
        s_addr[k][px][0] = yc0 * WD + xc0;
        s_addr[k][px][1] = yc0 * WD + xc1;
        s_addr[k][px][2] = yc1 * WD + xc0;
        s_addr[k][px][3] = yc1 * WD + xc1;
        s_w4[k][px][0] = (vy0 && vx0) ? wy0 * wx0 : 0.0;
        s_w4[k][px][1] = (vy0 && vx1) ? wy0 * wx1 : 0.0;
        s_w4[k][px][2] = (vy1 && vx0) ? wy1 * wx0 : 0.0;
        s_w4[k][px][3] = (vy1 && vx1) ? wy1 * wx1 : 0.0;
    }
    __syncthreads();

    double acc[4][4];
#pragma unroll
    for (int a = 0; a < 4; ++a)
#pragma unroll
        for (int p = 0; p < 4; ++p) acc[a][p] = 0.0;

    const ST* srcb = src + (size_t)b * src_bstride;
    for (int c0 = 0; c0 < Ci; c0 += CC) {
        // stage CC channels of bilinear samples
        for (int i = t; i < CC * 144; i += O) {
            int px = i % 16, k = (i / 16) % 9, c = i / 144;
            const ST* p = srcb + (size_t)(c0 + c) * HW;
            const int*    ad = s_addr[k][px];
            const double* w4 = s_w4[k][px];
            s_samp[c][k][px] = w4[0] * (double)p[ad[0]] + w4[1] * (double)p[ad[1]]
                             + w4[2] * (double)p[ad[2]] + w4[3] * (double)p[ad[3]];
        }
        __syncthreads();
        for (int c = 0; c < CC; ++c) {
#pragma unroll
            for (int k = 0; k < 9; ++k) {
                const float4 wv = *(const float4*)&wt[(size_t)((c0 + c) * 9 + k) * O + og * 4];
                const double* sp = &s_samp[c][k][pg * 4];
                double s0 = sp[0], s1 = sp[1], s2 = sp[2], s3 = sp[3];
                double w0 = (double)wv.x, w1 = (double)wv.y,
                       w2 = (double)wv.z, w3 = (double)wv.w;
                acc[0][0] = fma(w0, s0, acc[0][0]);
                acc[0][1] = fma(w0, s1, acc[0][1]);
                acc[0][2] = fma(w0, s2, acc[0][2]);
                acc[0][3] = fma(w0, s3, acc[0][3]);
                acc[1][0] = fma(w1, s0, acc[1][0]);
                acc[1][1] = fma(w1, s1, acc[1][1]);
                acc[1][2] = fma(w1, s2, acc[1][2]);
                acc[1][3] = fma(w1, s3, acc[1][3]);
                acc[2][0] = fma(w2, s0, acc[2][0]);
                acc[2][1] = fma(w2, s1, acc[2][1]);
                acc[2][2] = fma(w2, s2, acc[2][2]);
                acc[2][3] = fma(w2, s3, acc[2][3]);
                acc[3][0] = fma(w3, s0, acc[3][0]);
                acc[3][1] = fma(w3, s1, acc[3][1]);
                acc[3][2] = fma(w3, s2, acc[3][2]);
                acc[3][3] = fma(w3, s3, acc[3][3]);
            }
        }
        __syncthreads();
    }
#pragma unroll
    for (int oi = 0; oi < 4; ++oi) {
        double* d = dst + ((size_t)(b * O + og * 4 + oi) * HD + h) * WD + px0 + pg * 4;
#pragma unroll
        for (int pi = 0; pi < 4; ++pi) d[pi] = acc[oi][pi];
    }
}

// ---------------- fusion: cos-sim -> softmax -> blend, fp64 ------------------
__global__ void fuse_d(const double* __restrict__ d0, const double* __restrict__ d1,
                       const double* __restrict__ w0, const double* __restrict__ w1,
                       float* __restrict__ out) {
    int idx = blockIdx.x * 256 + threadIdx.x;
    if (idx >= BATCH * 128 * HW) return;
    int i = idx % HW;
    int b = idx / (128 * HW);
    double a  = w0[b * HW + i];
    double bb = w1[b * HW + i];
    double Wx = (a * bb) / sqrt(fmax((a * a) * (bb * bb), 1e-16));
    double Wy = (bb * bb) / sqrt(fmax((bb * bb) * (bb * bb), 1e-16));
    double m  = fmax(Wx, Wy);
    double e0 = exp(Wx - m), e1 = exp(Wy - m);
    double inv = 1.0 / (e0 + e1);
    out[idx] = (float)((d0[idx] * e0 + d1[idx] * e1) * inv);
}

// ---------------- launch -----------------------------------------------------
extern "C" void kernel_launch(void* const* d_in, const int* in_sizes, int n_in,
                              void* d_out, int out_size, void* d_ws, size_t ws_size,
                              hipStream_t stream) {
    const float* inputs = (const float*)d_in[2];
    const float* off_w[4] = {(const float*)d_in[3], (const float*)d_in[4],
                             (const float*)d_in[5], (const float*)d_in[6]};
    const float* def_w[3] = {(const float*)d_in[7], (const float*)d_in[8],
                             (const float*)d_in[9]};
    const float* pred_w = (const float*)d_in[10];
    const float* s_w[3] = {(const float*)d_in[11], (const float*)d_in[12],
                           (const float*)d_in[13]};
    float* out = (float*)d_out;

    // workspace layout (double units; fp32 regions at the end)
    double* ws = (double*)d_ws;
    size_t o = 0;
    double* featA   = ws + o; o += (size_t)BATCH * 256 * HW;
    double* featB   = ws + o; o += (size_t)BATCH * 256 * HW;
    double* offb    = ws + o; o += (size_t)BATCH * 18 * HW;
    double* offset0 = ws + o; o += (size_t)BATCH * 18 * HW;
    double* offset1 = ws + o; o += (size_t)BATCH * 18 * HW;
    double* deform0 = ws + o; o += (size_t)BATCH * 128 * HW;
    double* deform1 = ws + o; o += (size_t)BATCH * 128 * HW;
    double* s1      = ws + o; o += (size_t)BATCH * 64 * HW;
    double* s2      = ws + o; o += (size_t)BATCH * 32 * HW;
    double* w0buf   = ws + o; o += (size_t)BATCH * HW;
    double* w1buf   = ws + o; o += (size_t)BATCH * HW;
    float* wtdef0 = (float*)(ws + o); o += (size_t)256 * 256 * 9 / 2;
    float* wtdef1 = (float*)(ws + o); o += (size_t)256 * 256 * 9 / 2;
    float* wtdef2 = (float*)(ws + o); o += (size_t)256 * 256 * 9 / 2;
    float* wtpred = (float*)(ws + o); o += (size_t)128 * 128 * 9 / 2;
    if (ws_size < o * sizeof(double)) return;  // workspace too small

    auto cdiv = [](int a, int b) { return (a + b - 1) / b; };

    transpose_w_k<<<cdiv(256 * 256 * 9, 256), 256, 0, stream>>>(def_w[0], wtdef0, 256, 256);
    transpose_w_k<<<cdiv(256 * 256 * 9, 256), 256, 0, stream>>>(def_w[1], wtdef1, 256, 256);
    transpose_w_k<<<cdiv(256 * 256 * 9, 256), 256, 0, stream>>>(def_w[2], wtdef2, 256, 256);
    transpose_w_k<<<cdiv(128 * 128 * 9, 256), 256, 0, stream>>>(pred_w, wtpred, 128, 128);
    const float* wtdef[3] = {wtdef0, wtdef1, wtdef2};

    dim3 dgrid(WD / 16, HD, BATCH);
    dim3 ogrid(3, HD, BATCH);    // 18 outs = 3 x NO=6
    dim3 s1grid(8, HD, BATCH);   // 64 outs = 8 x NO=8
    dim3 s2grid(4, HD, BATCH);   // 32 outs = 4 x NO=8

    for (int branch = 0; branch < 2; ++branch) {
        int a0 = (branch == 0) ? 0 : 1;
        double* offsetN  = (branch == 0) ? offset0 : offset1;
        double* deformN  = (branch == 0) ? deform0 : deform1;
        double* wbufN    = (branch == 0) ? w0buf : w1buf;
        const float* xy  = (branch == 0) ? inputs : inputs + 128 * HW;

        pack_feat_d<<<cdiv(BATCH * 256 * HW, 256), 256, 0, stream>>>(inputs, featA, a0);

        double* cur = featA;
        double* nxt = featB;
        for (int i = 0; i < 3; ++i) {
            conv3x3_rowblk_d<6, 8><<<ogrid, 64, 0, stream>>>(
                cur, 256 * HW, off_w[i], offb, 256, 18, 0);
            deform_gemm_d<256, 32, double><<<dgrid, 256, 0, stream>>>(
                cur, 256 * HW, offb, wtdef[i], nxt, 256);
            double* tmp = cur; cur = nxt; nxt = tmp;
        }
        conv3x3_rowblk_d<6, 8><<<ogrid, 64, 0, stream>>>(
            cur, 256 * HW, off_w[3], offsetN, 256, 18, 0);

        deform_gemm_d<128, 32, float><<<dgrid, 128, 0, stream>>>(
            xy, 2 * 128 * HW, offsetN, wtpred, deformN, 128);

        conv3x3_rowblk_d<8, 8><<<s1grid, 64, 0, stream>>>(
            deformN, 128 * HW, s_w[0], s1, 128, 64, 1);
        conv3x3_rowblk_d<8, 8><<<s2grid, 64, 0, stream>>>(
            s1, 64 * HW, s_w[1], s2, 64, 32, 1);
        conv3x3_direct_d<<<cdiv(BATCH * 1 * HW, 256), 256, 0, stream>>>(
            s2, 32 * HW, s_w[2], wbufN, 32, 1, 1);
    }

    fuse_d<<<cdiv(BATCH * 128 * HW, 256), 256, 0, stream>>>(
        deform0, deform1, w0buf, w1buf, out);
}

// Round 7
// 3461.357 us; speedup vs baseline: 1.6533x; 1.6533x over previous
//
#include <hip/hip_runtime.h>

#define HD 64
#define WD 64
#define HW 4096
#define BATCH 2

// ---------------- weight transpose: w[o][c][k] -> wt[(c*9+k)*O + o] (fp32) ---
__global__ void transpose_w_k(const float* __restrict__ w, float* __restrict__ wt,
                              int O, int Ci) {
    int idx = blockIdx.x * 256 + threadIdx.x;
    int total = O * Ci * 9;
    if (idx >= total) return;
    int k = idx % 9;
    int c = (idx / 9) % Ci;
    int o = idx / (9 * Ci);
    wt[(size_t)(c * 9 + k) * O + o] = w[idx];
}

// ------------- offset-weight transpose: w[o][c][kk] -> owt[c][kk][20] --------
__global__ void transpose_ow_k(const float* __restrict__ w, float* __restrict__ owt) {
    int idx = blockIdx.x * 256 + threadIdx.x;
    if (idx >= 256 * 9 * 20) return;
    int k20 = idx % 20;
    int kk  = (idx / 20) % 9;
    int c   = idx / 180;
    owt[idx] = (k20 < 18) ? w[((size_t)k20 * 256 + c) * 9 + kk] : 0.f;
}

// ---------------- feat = concat(inputs[2b+a0], inputs[2b+1]) (f32 -> f64) ----
__global__ void pack_feat_d(const float* __restrict__ in, double* __restrict__ dst,
                            int a0) {
    int idx = blockIdx.x * 256 + threadIdx.x;
    if (idx >= BATCH * 256 * HW) return;
    int i = idx % HW;
    int c = (idx / HW) & 255;
    int b = idx / (HW * 256);
    int sb = 2 * b + ((c < 128) ? a0 : 1);
    dst[idx] = (double)in[((size_t)(sb * 128 + (c & 127))) * HW + i];
}

// ---------------- direct conv3x3, one thread per output, fp64 (S-net) --------
__global__ __launch_bounds__(256) void conv3x3_direct_d(
    const double* __restrict__ src, int bstride,
    const float* __restrict__ w, double* __restrict__ dst,
    int Ci, int O, int relu) {
    int idx = blockIdx.x * 256 + threadIdx.x;
    int total = BATCH * O * HW;
    if (idx >= total) return;
    int x = idx & (WD - 1);
    int h = (idx >> 6) & (HD - 1);
    int rest = idx >> 12;
    int o = rest % O;
    int b = rest / O;
    const double* s  = src + (size_t)b * bstride + h * WD + x;
    const float*  wo = w + (size_t)o * Ci * 9;
    bool ym = (h > 0), yp = (h < HD - 1);
    bool xm = (x > 0), xp = (x < WD - 1);
    double a0 = 0.0, a1 = 0.0, a2 = 0.0;
    for (int c = 0; c < Ci; ++c) {
        const double* sc = s + (size_t)c * HW;
        const float*  wc = wo + c * 9;
        if (ym) {
            double v0 = xm ? sc[-WD - 1] : 0.0;
            double v1 = sc[-WD];
            double v2 = xp ? sc[-WD + 1] : 0.0;
            a0 = fma(v0, (double)wc[0], a0);
            a0 = fma(v1, (double)wc[1], a0);
            a0 = fma(v2, (double)wc[2], a0);
        }
        {
            double v0 = xm ? sc[-1] : 0.0;
            double v1 = sc[0];
            double v2 = xp ? sc[1] : 0.0;
            a1 = fma(v0, (double)wc[3], a1);
            a1 = fma(v1, (double)wc[4], a1);
            a1 = fma(v2, (double)wc[5], a1);
        }
        if (yp) {
            double v0 = xm ? sc[WD - 1] : 0.0;
            double v1 = sc[WD];
            double v2 = xp ? sc[WD + 1] : 0.0;
            a2 = fma(v0, (double)wc[6], a2);
            a2 = fma(v1, (double)wc[7], a2);
            a2 = fma(v2, (double)wc[8], a2);
        }
    }
    double acc = (a0 + a1) + a2;
    if (relu) acc = fmax(acc, 0.0);
    dst[idx] = acc;
}

// ---------------- FUSED: offset-conv (18ch) + deformable conv GEMM, fp64 -----
// Block = O threads, one (b,h,16px) tile.
// Phase 0: offsets for this tile from csrc (256 ch) + owt [c][kk][20].
// Phase 1: bilinear addresses/weights. Phase 2: staged samples + reg-tile GEMM.
template <int O, int CC, typename ST>
__global__ __launch_bounds__(O) void fused_deform_d(
    const double* __restrict__ csrc,            // (B,256,H,W), bstride 256*HW
    const float*  __restrict__ owt,             // [c][kk][20]
    const ST* __restrict__ src, int src_bstride,
    const float* __restrict__ wt,               // [(c*9+k)*O + o]
    double* __restrict__ dst, int Ci) {
    constexpr int NCG = O / 16;        // channel groups for phase 0
    constexpr int CPG = 256 / NCG;     // channels per group
    static_assert(CC * 144 >= NCG * 288, "s_big too small for phase-0 partials");

    int px0 = blockIdx.x * 16;
    int h   = blockIdx.y;
    int b   = blockIdx.z;
    int t   = threadIdx.x;
    int og  = t >> 2;
    int pg  = t & 3;

    __shared__ double s_big[CC * 144];          // phase0 partials, then samples
    __shared__ int    s_addr[9][16][4];
    __shared__ double s_w4[9][16][4];
    __shared__ double s_off[18][16];

    // ---- phase 0: offset conv partials over this thread's channel slice ----
    {
        int px = t & 15, cg = t >> 4;
        int gx = px0 + px;
        double part[18];
#pragma unroll
        for (int k = 0; k < 18; ++k) part[k] = 0.0;
        const double* fb = csrc + (size_t)b * 256 * HW;
        bool ym = (h > 0), yp = (h < HD - 1), xm = (gx > 0), xp = (gx < WD - 1);
        for (int cc = 0; cc < CPG; ++cc) {
            int c = cg * CPG + cc;
            const double* fc = fb + (size_t)c * HW + h * WD + gx;
            double v[9];
            v[0] = (ym && xm) ? fc[-WD - 1] : 0.0;
            v[1] = ym ? fc[-WD] : 0.0;
            v[2] = (ym && xp) ? fc[-WD + 1] : 0.0;
            v[3] = xm ? fc[-1] : 0.0;
            v[4] = fc[0];
            v[5] = xp ? fc[1] : 0.0;
            v[6] = (yp && xm) ? fc[WD - 1] : 0.0;
            v[7] = yp ? fc[WD] : 0.0;
            v[8] = (yp && xp) ? fc[WD + 1] : 0.0;
            const float* wr = owt + (size_t)c * 180;
#pragma unroll
            for (int kk = 0; kk < 9; ++kk) {
                float wl[20];
                ((float4*)wl)[0] = *(const float4*)(wr + kk * 20);
                ((float4*)wl)[1] = *(const float4*)(wr + kk * 20 + 4);
                ((float4*)wl)[2] = *(const float4*)(wr + kk * 20 + 8);
                ((float4*)wl)[3] = *(const float4*)(wr + kk * 20 + 12);
                ((float4*)wl)[4] = *(const float4*)(wr + kk * 20 + 16);
                double vv = v[kk];
#pragma unroll
                for (int k = 0; k < 18; ++k)
                    part[k] = fma(vv, (double)wl[k], part[k]);
            }
        }
        double* s_part = s_big;                 // [NCG][18][16]
#pragma unroll
        for (int k = 0; k < 18; ++k) s_part[((size_t)cg * 18 + k) * 16 + px] = part[k];
    }
    __syncthreads();
    // ---- reduce partials -> s_off (deterministic ascending order) ----
    for (int i = t; i < 288; i += O) {
        int k = i >> 4, px = i & 15;
        double s = 0.0;
        for (int cg = 0; cg < NCG; ++cg) s += s_big[((size_t)cg * 18 + k) * 16 + px];
        s_off[k][px] = s;
    }
    __syncthreads();

    // ---- phase 1: 144 sampling positions ----
    for (int i = t; i < 144; i += O) {
        int k = i / 16, px = i % 16, wc = px0 + px;
        double dy = s_off[2 * k][px];
        double dx = s_off[2 * k + 1][px];
        double py  = dy + (double)(k / 3 - 1 + h);
        double pxf = dx + (double)(k % 3 - 1 + wc);
        double y0f = floor(py), x0f = floor(pxf);
        double wy1 = py - y0f, wx1 = pxf - x0f;
        double wy0 = 1.0 - wy1, wx0 = 1.0 - wx1;
        double y0c = fmax(-2.0, fmin(66.0, y0f));
        double x0c = fmax(-2.0, fmin(66.0, x0f));
        int y0 = (int)y0c, x0 = (int)x0c;
        int y1 = y0 + 1,   x1 = x0 + 1;
        bool vy0 = (y0 >= 0 && y0 < HD), vy1 = (y1 >= 0 && y1 < HD);
        bool vx0 = (x0 >= 0 && x0 < WD), vx1 = (x1 >= 0 && x1 < WD);
        int yc0 = min(max(y0, 0), HD - 1), yc1 = min(max(y1, 0), HD - 1);
        int xc0 = min(max(x0, 0), WD - 1), xc1 = min(max(x1, 0), WD - 1);
        s_addr[k][px][0] = yc0 * WD + xc0;
        s_addr[k][px][1] = yc0 * WD + xc1;
        s_addr[k][px][2] = yc1 * WD + xc0;
        s_addr[k][px][3] = yc1 * WD + xc1;
        s_w4[k][px][0] = (vy0 && vx0) ? wy0 * wx0 : 0.0;
        s_w4[k][px][1] = (vy0 && vx1) ? wy0 * wx1 : 0.0;
        s_w4[k][px][2] = (vy1 && vx0) ? wy1 * wx0 : 0.0;
        s_w4[k][px][3] = (vy1 && vx1) ? wy1 * wx1 : 0.0;
    }
    __syncthreads();

    // ---- phase 2: staged bilinear samples + register-tile GEMM ----
    double acc[4][4];
#pragma unroll
    for (int a = 0; a < 4; ++a)
#pragma unroll
        for (int p = 0; p < 4; ++p) acc[a][p] = 0.0;

    double (*s_samp)[9][16] = (double (*)[9][16])s_big;
    const ST* srcb = src + (size_t)b * src_bstride;
    for (int c0 = 0; c0 < Ci; c0 += CC) {
        for (int i = t; i < CC * 144; i += O) {
            int px = i % 16, k = (i / 16) % 9, c = i / 144;
            const ST* p = srcb + (size_t)(c0 + c) * HW;
            const int*    ad = s_addr[k][px];
            const double* w4 = s_w4[k][px];
            s_samp[c][k][px] = w4[0] * (double)p[ad[0]] + w4[1] * (double)p[ad[1]]
                             + w4[2] * (double)p[ad[2]] + w4[3] * (double)p[ad[3]];
        }
        __syncthreads();
        for (int c = 0; c < CC; ++c) {
#pragma unroll
            for (int k = 0; k < 9; ++k) {
                const float4 wv = *(const float4*)&wt[(size_t)((c0 + c) * 9 + k) * O + og * 4];
                const double* sp = &s_samp[c][k][pg * 4];
                double s0 = sp[0], s1 = sp[1], s2 = sp[2], s3 = sp[3];
                double w0 = (double)wv.x, w1 = (double)wv.y,
                       w2 = (double)wv.z, w3 = (double)wv.w;
                acc[0][0] = fma(w0, s0, acc[0][0]);
                acc[0][1] = fma(w0, s1, acc[0][1]);
                acc[0][2] = fma(w0, s2, acc[0][2]);
                acc[0][3] = fma(w0, s3, acc[0][3]);
                acc[1][0] = fma(w1, s0, acc[1][0]);
                acc[1][1] = fma(w1, s1, acc[1][1]);
                acc[1][2] = fma(w1, s2, acc[1][2]);
                acc[1][3] = fma(w1, s3, acc[1][3]);
                acc[2][0] = fma(w2, s0, acc[2][0]);
                acc[2][1] = fma(w2, s1, acc[2][1]);
                acc[2][2] = fma(w2, s2, acc[2][2]);
                acc[2][3] = fma(w2, s3, acc[2][3]);
                acc[3][0] = fma(w3, s0, acc[3][0]);
                acc[3][1] = fma(w3, s1, acc[3][1]);
                acc[3][2] = fma(w3, s2, acc[3][2]);
                acc[3][3] = fma(w3, s3, acc[3][3]);
            }
        }
        __syncthreads();
    }
#pragma unroll
    for (int oi = 0; oi < 4; ++oi) {
        double* d = dst + ((size_t)(b * O + og * 4 + oi) * HD + h) * WD + px0 + pg * 4;
#pragma unroll
        for (int pi = 0; pi < 4; ++pi) d[pi] = acc[oi][pi];
    }
}

// ---------------- fusion: cos-sim -> softmax -> blend, fp64 ------------------
__global__ void fuse_d(const double* __restrict__ d0, const double* __restrict__ d1,
                       const double* __restrict__ w0, const double* __restrict__ w1,
                       float* __restrict__ out) {
    int idx = blockIdx.x * 256 + threadIdx.x;
    if (idx >= BATCH * 128 * HW) return;
    int i = idx % HW;
    int b = idx / (128 * HW);
    double a  = w0[b * HW + i];
    double bb = w1[b * HW + i];
    double Wx = (a * bb) / sqrt(fmax((a * a) * (bb * bb), 1e-16));
    double Wy = (bb * bb) / sqrt(fmax((bb * bb) * (bb * bb), 1e-16));
    double m  = fmax(Wx, Wy);
    double e0 = exp(Wx - m), e1 = exp(Wy - m);
    double inv = 1.0 / (e0 + e1);
    out[idx] = (float)((d0[idx] * e0 + d1[idx] * e1) * inv);
}

// ---------------- launch -----------------------------------------------------
extern "C" void kernel_launch(void* const* d_in, const int* in_sizes, int n_in,
                              void* d_out, int out_size, void* d_ws, size_t ws_size,
                              hipStream_t stream) {
    const float* inputs = (const float*)d_in[2];
    const float* off_w[4] = {(const float*)d_in[3], (const float*)d_in[4],
                             (const float*)d_in[5], (const float*)d_in[6]};
    const float* def_w[3] = {(const float*)d_in[7], (const float*)d_in[8],
                             (const float*)d_in[9]};
    const float* pred_w = (const float*)d_in[10];
    const float* s_w[3] = {(const float*)d_in[11], (const float*)d_in[12],
                           (const float*)d_in[13]};
    float* out = (float*)d_out;

    // workspace layout (double units; fp32 regions at the end)
    double* ws = (double*)d_ws;
    size_t o = 0;
    double* featA   = ws + o; o += (size_t)BATCH * 256 * HW;
    double* featB   = ws + o; o += (size_t)BATCH * 256 * HW;
    double* deform0 = ws + o; o += (size_t)BATCH * 128 * HW;
    double* deform1 = ws + o; o += (size_t)BATCH * 128 * HW;
    double* s1      = ws + o; o += (size_t)BATCH * 64 * HW;
    double* s2      = ws + o; o += (size_t)BATCH * 32 * HW;
    double* w0buf   = ws + o; o += (size_t)BATCH * HW;
    double* w1buf   = ws + o; o += (size_t)BATCH * HW;
    float* wtdef0 = (float*)(ws + o); o += (size_t)256 * 256 * 9 / 2;
    float* wtdef1 = (float*)(ws + o); o += (size_t)256 * 256 * 9 / 2;
    float* wtdef2 = (float*)(ws + o); o += (size_t)256 * 256 * 9 / 2;
    float* wtpred = (float*)(ws + o); o += (size_t)128 * 128 * 9 / 2;
    float* owt0   = (float*)(ws + o); o += (size_t)256 * 9 * 20 / 2;
    float* owt1   = (float*)(ws + o); o += (size_t)256 * 9 * 20 / 2;
    float* owt2   = (float*)(ws + o); o += (size_t)256 * 9 * 20 / 2;
    float* owt3   = (float*)(ws + o); o += (size_t)256 * 9 * 20 / 2;
    if (ws_size < o * sizeof(double)) return;  // workspace too small

    auto cdiv = [](int a, int b) { return (a + b - 1) / b; };

    transpose_w_k<<<cdiv(256 * 256 * 9, 256), 256, 0, stream>>>(def_w[0], wtdef0, 256, 256);
    transpose_w_k<<<cdiv(256 * 256 * 9, 256), 256, 0, stream>>>(def_w[1], wtdef1, 256, 256);
    transpose_w_k<<<cdiv(256 * 256 * 9, 256), 256, 0, stream>>>(def_w[2], wtdef2, 256, 256);
    transpose_w_k<<<cdiv(128 * 128 * 9, 256), 256, 0, stream>>>(pred_w, wtpred, 128, 128);
    transpose_ow_k<<<cdiv(256 * 9 * 20, 256), 256, 0, stream>>>(off_w[0], owt0);
    transpose_ow_k<<<cdiv(256 * 9 * 20, 256), 256, 0, stream>>>(off_w[1], owt1);
    transpose_ow_k<<<cdiv(256 * 9 * 20, 256), 256, 0, stream>>>(off_w[2], owt2);
    transpose_ow_k<<<cdiv(256 * 9 * 20, 256), 256, 0, stream>>>(off_w[3], owt3);
    const float* wtdef[3] = {wtdef0, wtdef1, wtdef2};
    const float* owt[4]   = {owt0, owt1, owt2, owt3};

    dim3 dgrid(WD / 16, HD, BATCH);

    for (int branch = 0; branch < 2; ++branch) {
        int a0 = (branch == 0) ? 0 : 1;
        double* deformN  = (branch == 0) ? deform0 : deform1;
        double* wbufN    = (branch == 0) ? w0buf : w1buf;
        const float* xy  = (branch == 0) ? inputs : inputs + 128 * HW;

        pack_feat_d<<<cdiv(BATCH * 256 * HW, 256), 256, 0, stream>>>(inputs, featA, a0);

        double* cur = featA;
        double* nxt = featB;
        for (int i = 0; i < 3; ++i) {
            fused_deform_d<256, 32, double><<<dgrid, 256, 0, stream>>>(
                cur, owt[i], cur, 256 * HW, wtdef[i], nxt, 256);
            double* tmp = cur; cur = nxt; nxt = tmp;
        }
        // pred deform: offsets from 4th conv on final feat; sample raw fp32 x/y
        fused_deform_d<128, 32, float><<<dgrid, 128, 0, stream>>>(
            cur, owt[3], xy, 2 * 128 * HW, wtpred, deformN, 128);

        conv3x3_direct_d<<<cdiv(BATCH * 64 * HW, 256), 256, 0, stream>>>(
            deformN, 128 * HW, s_w[0], s1, 128, 64, 1);
        conv3x3_direct_d<<<cdiv(BATCH * 32 * HW, 256), 256, 0, stream>>>(
            s1, 64 * HW, s_w[1], s2, 64, 32, 1);
        conv3x3_direct_d<<<cdiv(BATCH * 1 * HW, 256), 256, 0, stream>>>(
            s2, 32 * HW, s_w[2], wbufN, 32, 1, 1);
    }

    fuse_d<<<cdiv(BATCH * 128 * HW, 256), 256, 0, stream>>>(
        deform0, deform1, w0buf, w1buf, out);
}

// Round 8
// 3043.061 us; speedup vs baseline: 1.8806x; 1.1375x over previous
//
#include <hip/hip_runtime.h>

#define HD 64
#define WD 64
#define HW 4096
#define BATCH 2
#define NSLOT 4   // (branch, batch) merged slots: s = br*2 + b

// ---- merged def-weight transpose: w[o][c][k] -> wt[which][(c*9+k)*256 + o] --
__global__ void transpose_w3_k(const float* __restrict__ w0, const float* __restrict__ w1,
                               const float* __restrict__ w2, float* __restrict__ wt) {
    const int N = 256 * 256 * 9;
    int idx = blockIdx.x * 256 + threadIdx.x;
    if (idx >= 3 * N) return;
    int which = idx / N, r = idx % N;
    const float* w = (which == 0) ? w0 : (which == 1) ? w1 : w2;
    int k = r % 9;
    int c = (r / 9) % 256;
    int o = r / (9 * 256);
    wt[(size_t)which * N + (size_t)(c * 9 + k) * 256 + o] = w[r];
}

__global__ void transpose_wp_k(const float* __restrict__ w, float* __restrict__ wt) {
    int idx = blockIdx.x * 256 + threadIdx.x;
    if (idx >= 128 * 128 * 9) return;
    int k = idx % 9;
    int c = (idx / 9) % 128;
    int o = idx / (9 * 128);
    wt[(size_t)(c * 9 + k) * 128 + o] = w[idx];
}

// ---- merged offset-weight transpose: w[o][c][kk] -> owt[which][c][kk][20] ---
__global__ void transpose_ow4_k(const float* __restrict__ w0, const float* __restrict__ w1,
                                const float* __restrict__ w2, const float* __restrict__ w3,
                                float* __restrict__ owt) {
    const int N = 256 * 180;
    int idx = blockIdx.x * 256 + threadIdx.x;
    if (idx >= 4 * N) return;
    int which = idx / N, r = idx % N;
    const float* w = (which == 0) ? w0 : (which == 1) ? w1 : (which == 2) ? w2 : w3;
    int k20 = r % 20;
    int kk  = (r / 20) % 9;
    int c   = r / 180;
    owt[idx] = (k20 < 18) ? w[((size_t)k20 * 256 + c) * 9 + kk] : 0.f;
}

// ---- pack 4 slots: slot s=br*2+b, c<128 -> img 2b+br ; c>=128 -> img 2b+1 ---
__global__ void pack_feat4_d(const float* __restrict__ in, double* __restrict__ dst) {
    int idx = blockIdx.x * 256 + threadIdx.x;
    if (idx >= NSLOT * 256 * HW) return;
    int i = idx % HW;
    int c = (idx / HW) & 255;
    int s = idx / (256 * HW);
    int b = s & 1, br = s >> 1;
    int img = (c < 128) ? (2 * b + br) : (2 * b + 1);
    dst[idx] = (double)in[((size_t)(img * 128 + (c & 127))) * HW + i];
}

// ---------------- FUSED offset-conv + deformable GEMM, fp64 ------------------
// Grid (4, HD, NSLOT); block O threads. CC=16.
template <int O, int CC, bool PRED>
__global__ __launch_bounds__(O) void fused_deform_d(
    const double* __restrict__ csrc,            // (NSLOT,256,HW) offset source
    const float*  __restrict__ owt,             // [c][kk][20]
    const float*  __restrict__ fsrc,            // raw inputs (PRED only)
    const float*  __restrict__ wt,              // [(c*9+k)*O + o]
    double* __restrict__ dst, int Ci) {
    constexpr int NCGT = O / 16;       // 16 (O=256) or 8 (O=128)
    constexpr int CPG  = 256 / NCGT;   // 16 or 32
    static_assert(CC * 144 >= 8 * 288, "phase-0 partial buffer");

    int px0 = blockIdx.x * 16;
    int h   = blockIdx.y;
    int s   = blockIdx.z;
    int t   = threadIdx.x;
    int og  = t >> 2;
    int pg  = t & 3;

    __shared__ double s_big[CC * 144];          // phase0 partials, then samples
    __shared__ int    s_addr[9][16][4];
    __shared__ double s_w4[9][16][4];
    __shared__ double s_off[18][16];

    // ---- phase 0: offset conv; every thread computes CPG channels in regs ---
    {
        int px = t & 15, cg = t >> 4;
        int gx = px0 + px;
        double part[18];
#pragma unroll
        for (int k = 0; k < 18; ++k) part[k] = 0.0;
        const double* fb = csrc + (size_t)s * 256 * HW;
        bool ym = (h > 0), yp = (h < HD - 1), xm = (gx > 0), xp = (gx < WD - 1);
        for (int cc = 0; cc < CPG; ++cc) {
            int c = cg * CPG + cc;
            const double* fc = fb + (size_t)c * HW + h * WD + gx;
            double v[9];
            v[0] = (ym && xm) ? fc[-WD - 1] : 0.0;
            v[1] = ym ? fc[-WD] : 0.0;
            v[2] = (ym && xp) ? fc[-WD + 1] : 0.0;
            v[3] = xm ? fc[-1] : 0.0;
            v[4] = fc[0];
            v[5] = xp ? fc[1] : 0.0;
            v[6] = (yp && xm) ? fc[WD - 1] : 0.0;
            v[7] = yp ? fc[WD] : 0.0;
            v[8] = (yp && xp) ? fc[WD + 1] : 0.0;
            const float* wr = owt + (size_t)c * 180;
#pragma unroll
            for (int kk = 0; kk < 9; ++kk) {
                float wl[20];
                ((float4*)wl)[0] = *(const float4*)(wr + kk * 20);
                ((float4*)wl)[1] = *(const float4*)(wr + kk * 20 + 4);
                ((float4*)wl)[2] = *(const float4*)(wr + kk * 20 + 8);
                ((float4*)wl)[3] = *(const float4*)(wr + kk * 20 + 12);
                ((float4*)wl)[4] = *(const float4*)(wr + kk * 20 + 16);
                double vv = v[kk];
#pragma unroll
                for (int k = 0; k < 18; ++k)
                    part[k] = fma(vv, (double)wl[k], part[k]);
            }
        }
        double* s_part = s_big;                 // [8][18][16]
        if constexpr (NCGT == 16) {
            if (cg < 8) {
#pragma unroll
                for (int k = 0; k < 18; ++k)
                    s_part[((size_t)cg * 18 + k) * 16 + px] = part[k];
            }
            __syncthreads();
            for (int i = t; i < 288; i += O) {
                int k = i >> 4, p2 = i & 15;
                double ssum = 0.0;
                for (int g = 0; g < 8; ++g) ssum += s_part[((size_t)g * 18 + k) * 16 + p2];
                s_off[k][p2] = ssum;
            }
            __syncthreads();
            if (cg >= 8) {
#pragma unroll
                for (int k = 0; k < 18; ++k)
                    s_part[((size_t)(cg - 8) * 18 + k) * 16 + px] = part[k];
            }
            __syncthreads();
            for (int i = t; i < 288; i += O) {
                int k = i >> 4, p2 = i & 15;
                double ssum = 0.0;
                for (int g = 0; g < 8; ++g) ssum += s_part[((size_t)g * 18 + k) * 16 + p2];
                s_off[k][p2] += ssum;
            }
        } else {
#pragma unroll
            for (int k = 0; k < 18; ++k)
                s_part[((size_t)cg * 18 + k) * 16 + px] = part[k];
            __syncthreads();
            for (int i = t; i < 288; i += O) {
                int k = i >> 4, p2 = i & 15;
                double ssum = 0.0;
                for (int g = 0; g < 8; ++g) ssum += s_part[((size_t)g * 18 + k) * 16 + p2];
                s_off[k][p2] = ssum;
            }
        }
    }
    __syncthreads();

    // ---- phase 1: 144 sampling positions ----
    for (int i = t; i < 144; i += O) {
        int k = i / 16, px = i % 16, wc = px0 + px;
        double dy = s_off[2 * k][px];
        double dx = s_off[2 * k + 1][px];
        double py  = dy + (double)(k / 3 - 1 + h);
        double pxf = dx + (double)(k % 3 - 1 + wc);
        double y0f = floor(py), x0f = floor(pxf);
        double wy1 = py - y0f, wx1 = pxf - x0f;
        double wy0 = 1.0 - wy1, wx0 = 1.0 - wx1;
        double y0c = fmax(-2.0, fmin(66.0, y0f));
        double x0c = fmax(-2.0, fmin(66.0, x0f));
        int y0 = (int)y0c, x0 = (int)x0c;
        int y1 = y0 + 1,   x1 = x0 + 1;
        bool vy0 = (y0 >= 0 && y0 < HD), vy1 = (y1 >= 0 && y1 < HD);
        bool vx0 = (x0 >= 0 && x0 < WD), vx1 = (x1 >= 0 && x1 < WD);
        int yc0 = min(max(y0, 0), HD - 1), yc1 = min(max(y1, 0), HD - 1);
        int xc0 = min(max(x0, 0), WD - 1), xc1 = min(max(x1, 0), WD - 1);
        s_addr[k][px][0] = yc0 * WD + xc0;
        s_addr[k][px][1] = yc0 * WD + xc1;
        s_addr[k][px][2] = yc1 * WD + xc0;
        s_addr[k][px][3] = yc1 * WD + xc1;
        s_w4[k][px][0] = (vy0 && vx0) ? wy0 * wx0 : 0.0;
        s_w4[k][px][1] = (vy0 && vx1) ? wy0 * wx1 : 0.0;
        s_w4[k][px][2] = (vy1 && vx0) ? wy1 * wx0 : 0.0;
        s_w4[k][px][3] = (vy1 && vx1) ? wy1 * wx1 : 0.0;
    }
    __syncthreads();

    // ---- phase 2: staged bilinear samples + register-tile GEMM ----
    double acc[4][4];
#pragma unroll
    for (int a = 0; a < 4; ++a)
#pragma unroll
        for (int p = 0; p < 4; ++p) acc[a][p] = 0.0;

    double (*s_samp)[9][16] = (double (*)[9][16])s_big;
    int b = s & 1, br = s >> 1;
    const double* srcb_d = csrc + (size_t)s * 256 * HW;
    const float*  srcb_f = PRED ? (fsrc + (size_t)(2 * b + br) * 128 * HW) : nullptr;

    for (int c0 = 0; c0 < Ci; c0 += CC) {
        for (int i = t; i < CC * 144; i += O) {
            int px = i % 16, k = (i / 16) % 9, c = i / 144;
            const int*    ad = s_addr[k][px];
            const double* w4 = s_w4[k][px];
            double v;
            if constexpr (PRED) {
                const float* p = srcb_f + (size_t)(c0 + c) * HW;
                v = w4[0] * (double)p[ad[0]] + w4[1] * (double)p[ad[1]]
                  + w4[2] * (double)p[ad[2]] + w4[3] * (double)p[ad[3]];
            } else {
                const double* p = srcb_d + (size_t)(c0 + c) * HW;
                v = w4[0] * p[ad[0]] + w4[1] * p[ad[1]]
                  + w4[2] * p[ad[2]] + w4[3] * p[ad[3]];
            }
            s_samp[c][k][px] = v;
        }
        __syncthreads();
        for (int c = 0; c < CC; ++c) {
#pragma unroll
            for (int k = 0; k < 9; ++k) {
                const float4 wv = *(const float4*)&wt[(size_t)((c0 + c) * 9 + k) * O + og * 4];
                const double* sp = &s_samp[c][k][pg * 4];
                double s0 = sp[0], s1 = sp[1], s2 = sp[2], s3 = sp[3];
                double w0 = (double)wv.x, w1 = (double)wv.y,
                       w2 = (double)wv.z, w3 = (double)wv.w;
                acc[0][0] = fma(w0, s0, acc[0][0]);
                acc[0][1] = fma(w0, s1, acc[0][1]);
                acc[0][2] = fma(w0, s2, acc[0][2]);
                acc[0][3] = fma(w0, s3, acc[0][3]);
                acc[1][0] = fma(w1, s0, acc[1][0]);
                acc[1][1] = fma(w1, s1, acc[1][1]);
                acc[1][2] = fma(w1, s2, acc[1][2]);
                acc[1][3] = fma(w1, s3, acc[1][3]);
                acc[2][0] = fma(w2, s0, acc[2][0]);
                acc[2][1] = fma(w2, s1, acc[2][1]);
                acc[2][2] = fma(w2, s2, acc[2][2]);
                acc[2][3] = fma(w2, s3, acc[2][3]);
                acc[3][0] = fma(w3, s0, acc[3][0]);
                acc[3][1] = fma(w3, s1, acc[3][1]);
                acc[3][2] = fma(w3, s2, acc[3][2]);
                acc[3][3] = fma(w3, s3, acc[3][3]);
            }
        }
        __syncthreads();
    }
#pragma unroll
    for (int oi = 0; oi < 4; ++oi) {
        double* d = dst + ((size_t)(s * O + og * 4 + oi) * HD + h) * WD + px0 + pg * 4;
#pragma unroll
        for (int pi = 0; pi < 4; ++pi) d[pi] = acc[oi][pi];
    }
}

// ---------------- S-net conv3x3: 4 outputs per thread, fp64 ------------------
// Block covers 256 px of one (img, og). o = og*4+oi wave-uniform.
__global__ __launch_bounds__(256) void conv3x3_s4_d(
    const double* __restrict__ src, const float* __restrict__ w,
    double* __restrict__ dst, int Ci, int O, int relu) {
    int idx = blockIdx.x * 256 + threadIdx.x;
    int px   = idx & 4095;
    int rest = idx >> 12;
    int og   = rest % (O >> 2);
    int img  = rest / (O >> 2);
    if (img >= NSLOT) return;
    int x = px & 63, h = px >> 6;
    const double* sb = src + (size_t)img * Ci * HW + h * WD + x;
    bool ym = (h > 0), yp = (h < HD - 1), xm = (x > 0), xp = (x < WD - 1);
    double acc[4] = {0.0, 0.0, 0.0, 0.0};
    for (int c = 0; c < Ci; ++c) {
        const double* sc = sb + (size_t)c * HW;
        double v[9];
        v[0] = (ym && xm) ? sc[-WD - 1] : 0.0;
        v[1] = ym ? sc[-WD] : 0.0;
        v[2] = (ym && xp) ? sc[-WD + 1] : 0.0;
        v[3] = xm ? sc[-1] : 0.0;
        v[4] = sc[0];
        v[5] = xp ? sc[1] : 0.0;
        v[6] = (yp && xm) ? sc[WD - 1] : 0.0;
        v[7] = yp ? sc[WD] : 0.0;
        v[8] = (yp && xp) ? sc[WD + 1] : 0.0;
#pragma unroll
        for (int oi = 0; oi < 4; ++oi) {
            const float* wc = w + ((size_t)(og * 4 + oi) * Ci + c) * 9;
#pragma unroll
            for (int k = 0; k < 9; ++k)
                acc[oi] = fma(v[k], (double)wc[k], acc[oi]);
        }
    }
#pragma unroll
    for (int oi = 0; oi < 4; ++oi) {
        double vv = acc[oi];
        if (relu) vv = fmax(vv, 0.0);
        dst[((size_t)(img * O + og * 4 + oi)) * HW + px] = vv;
    }
}

// ---------------- direct conv3x3 (final O=1 S-conv), 4 imgs ------------------
__global__ __launch_bounds__(256) void conv3x3_direct_d(
    const double* __restrict__ src, const float* __restrict__ w,
    double* __restrict__ dst, int Ci, int O, int relu) {
    int idx = blockIdx.x * 256 + threadIdx.x;
    int total = NSLOT * O * HW;
    if (idx >= total) return;
    int x = idx & (WD - 1);
    int h = (idx >> 6) & (HD - 1);
    int rest = idx >> 12;
    int o = rest % O;
    int img = rest / O;
    const double* s  = src + (size_t)img * Ci * HW + h * WD + x;
    const float*  wo = w + (size_t)o * Ci * 9;
    bool ym = (h > 0), yp = (h < HD - 1), xm = (x > 0), xp = (x < WD - 1);
    double a0 = 0.0, a1 = 0.0, a2 = 0.0;
    for (int c = 0; c < Ci; ++c) {
        const double* sc = s + (size_t)c * HW;
        const float*  wc = wo + c * 9;
        if (ym) {
            double v0 = xm ? sc[-WD - 1] : 0.0;
            double v1 = sc[-WD];
            double v2 = xp ? sc[-WD + 1] : 0.0;
            a0 = fma(v0, (double)wc[0], a0);
            a0 = fma(v1, (double)wc[1], a0);
            a0 = fma(v2, (double)wc[2], a0);
        }
        {
            double v0 = xm ? sc[-1] : 0.0;
            double v1 = sc[0];
            double v2 = xp ? sc[1] : 0.0;
            a1 = fma(v0, (double)wc[3], a1);
            a1 = fma(v1, (double)wc[4], a1);
            a1 = fma(v2, (double)wc[5], a1);
        }
        if (yp) {
            double v0 = xm ? sc[WD - 1] : 0.0;
            double v1 = sc[WD];
            double v2 = xp ? sc[WD + 1] : 0.0;
            a2 = fma(v0, (double)wc[6], a2);
            a2 = fma(v1, (double)wc[7], a2);
            a2 = fma(v2, (double)wc[8], a2);
        }
    }
    double acc = (a0 + a1) + a2;
    if (relu) acc = fmax(acc, 0.0);
    dst[idx] = acc;
}

// ---------------- fusion: cos-sim -> softmax -> blend, fp64 ------------------
__global__ void fuse_d(const double* __restrict__ dfm,   // (4,128,HW)
                       const double* __restrict__ wbuf,  // (4,HW)
                       float* __restrict__ out) {
    int idx = blockIdx.x * 256 + threadIdx.x;
    if (idx >= BATCH * 128 * HW) return;
    int i = idx % HW;
    int b = idx / (128 * HW);
    double a  = wbuf[(size_t)b * HW + i];
    double bb = wbuf[(size_t)(2 + b) * HW + i];
    double Wx = (a * bb) / sqrt(fmax((a * a) * (bb * bb), 1e-16));
    double Wy = (bb * bb) / sqrt(fmax((bb * bb) * (bb * bb), 1e-16));
    double m  = fmax(Wx, Wy);
    double e0 = exp(Wx - m), e1 = exp(Wy - m);
    double inv = 1.0 / (e0 + e1);
    double d0 = dfm[idx];
    double d1 = dfm[(size_t)2 * 128 * HW + idx];
    out[idx] = (float)((d0 * e0 + d1 * e1) * inv);
}

// ---------------- launch -----------------------------------------------------
extern "C" void kernel_launch(void* const* d_in, const int* in_sizes, int n_in,
                              void* d_out, int out_size, void* d_ws, size_t ws_size,
                              hipStream_t stream) {
    const float* inputs = (const float*)d_in[2];
    const float* off_w[4] = {(const float*)d_in[3], (const float*)d_in[4],
                             (const float*)d_in[5], (const float*)d_in[6]};
    const float* def_w[3] = {(const float*)d_in[7], (const float*)d_in[8],
                             (const float*)d_in[9]};
    const float* pred_w = (const float*)d_in[10];
    const float* s_w[3] = {(const float*)d_in[11], (const float*)d_in[12],
                           (const float*)d_in[13]};
    float* out = (float*)d_out;

    // workspace (double units)
    double* ws = (double*)d_ws;
    size_t o = 0;
    double* featA = ws + o; o += (size_t)NSLOT * 256 * HW;   // also holds deform/s1/s2/wbuf later
    double* featB = ws + o; o += (size_t)NSLOT * 256 * HW;
    float* wtdef  = (float*)(ws + o); o += (size_t)3 * 256 * 256 * 9 / 2;
    float* wtpred = (float*)(ws + o); o += (size_t)128 * 128 * 9 / 2;
    float* owt    = (float*)(ws + o); o += (size_t)4 * 256 * 180 / 2;
    if (ws_size < o * sizeof(double)) return;

    // featA sub-regions reused after it is dead (post 3rd deform iteration)
    double* deform = featA;                                  // (4,128,HW)
    double* s1     = featA + (size_t)NSLOT * 128 * HW;       // (4,64,HW)
    double* s2     = s1    + (size_t)NSLOT * 64 * HW;        // (4,32,HW)
    double* wbuf   = s2    + (size_t)NSLOT * 32 * HW;        // (4,HW)

    auto cdiv = [](int a, int b) { return (a + b - 1) / b; };

    transpose_w3_k<<<cdiv(3 * 256 * 256 * 9, 256), 256, 0, stream>>>(
        def_w[0], def_w[1], def_w[2], wtdef);
    transpose_wp_k<<<cdiv(128 * 128 * 9, 256), 256, 0, stream>>>(pred_w, wtpred);
    transpose_ow4_k<<<cdiv(4 * 256 * 180, 256), 256, 0, stream>>>(
        off_w[0], off_w[1], off_w[2], off_w[3], owt);

    pack_feat4_d<<<cdiv(NSLOT * 256 * HW, 256), 256, 0, stream>>>(inputs, featB);
    // NOTE: first iteration reads featB, writes featA; after iter 3 cur=featA? track below.

    dim3 dgrid(WD / 16, HD, NSLOT);

    // iterate: cur -> nxt (3 deform convs). Start cur=featB so featA frees last.
    double* cur = featB;
    double* nxt = featA;
    for (int i = 0; i < 3; ++i) {
        fused_deform_d<256, 16, false><<<dgrid, 256, 0, stream>>>(
            cur, owt + (size_t)i * 256 * 180, nullptr,
            wtdef + (size_t)i * 256 * 256 * 9, nxt, 256);
        double* tmp = cur; cur = nxt; nxt = tmp;
    }
    // after 3 iters: cur = featA?  featB->featA (i0), featA->featB (i1), featB->featA (i2)
    // => cur = featA, featB dead.  Reuse featB for outputs instead of featA!
    deform = featB;
    s1     = featB + (size_t)NSLOT * 128 * HW;
    s2     = s1    + (size_t)NSLOT * 64 * HW;
    wbuf   = s2    + (size_t)NSLOT * 32 * HW;

    // pred deform: offsets from cur (=featA), samples raw fp32 inputs
    fused_deform_d<128, 16, true><<<dgrid, 128, 0, stream>>>(
        cur, owt + (size_t)3 * 256 * 180, inputs, wtpred, deform, 128);

    conv3x3_s4_d<<<cdiv(NSLOT * 16 * HW, 256), 256, 0, stream>>>(
        deform, s_w[0], s1, 128, 64, 1);
    conv3x3_s4_d<<<cdiv(NSLOT * 8 * HW, 256), 256, 0, stream>>>(
        s1, s_w[1], s2, 64, 32, 1);
    conv3x3_direct_d<<<cdiv(NSLOT * 1 * HW, 256), 256, 0, stream>>>(
        s2, s_w[2], wbuf, 32, 1, 1);

    fuse_d<<<cdiv(BATCH * 128 * HW, 256), 256, 0, stream>>>(deform, wbuf, out);
}